// Round 16
// baseline (97.793 us; speedup 1.0000x reference)
//
#include <hip/hip_runtime.h>

#define CB 256   // batch
#define CR 1152  // routes
#define CC 10    // class capsules
#define CO 16    // out dim
#define CI 8     // in dim
#define CK (CR*CI)   // 9216
#define NCO (CC*CO)  // 160

typedef __bf16 bf16_t;
typedef __attribute__((ext_vector_type(8))) __bf16 bf16x8;
typedef __attribute__((ext_vector_type(4))) float f32x4;

__device__ __forceinline__ unsigned short bfbits(float f) {
  union { __bf16 h; unsigned short u; } u; u.h = (bf16_t)f; return u.u;
}

// ---------------- cvt: pure-BW, fully coalesced reads ----------------
__global__ __launch_bounds__(256) void k_cvt(const float* __restrict__ x,
                                             const float* __restrict__ W,
                                             bf16_t* __restrict__ xb,
                                             bf16_t* __restrict__ Wt) {
  const int idx = blockIdx.x * 256 + threadIdx.x;
  const int NX = CB * CK / 8;              // 294912
  if (idx < NX) {
    const float4 f0 = ((const float4*)x)[idx * 2];
    const float4 f1 = ((const float4*)x)[idx * 2 + 1];
    bf16x8 o;
    o[0] = (bf16_t)f0.x; o[1] = (bf16_t)f0.y; o[2] = (bf16_t)f0.z; o[3] = (bf16_t)f0.w;
    o[4] = (bf16_t)f1.x; o[5] = (bf16_t)f1.y; o[6] = (bf16_t)f1.z; o[7] = (bf16_t)f1.w;
    ((bf16x8*)xb)[idx] = o;
  } else {
    const int wi = idx - NX;               // 0..184319, co fastest
    const int co = wi % NCO;               // c*16+o
    const int r  = wi / NCO;
    const float4* src = (const float4*)(W + ((size_t)r * NCO + co) * CI);
    const float4 f0 = src[0], f1 = src[1];
    bf16x8 v;
    v[0] = (bf16_t)f0.x; v[1] = (bf16_t)f0.y; v[2] = (bf16_t)f0.z; v[3] = (bf16_t)f0.w;
    v[4] = (bf16_t)f1.x; v[5] = (bf16_t)f1.y; v[6] = (bf16_t)f1.z; v[7] = (bf16_t)f1.w;
    *(bf16x8*)(Wt + (size_t)co * CK + r * 8) = v;
  }
}

// ---------------- s + squash: pure MFMA from xb / (Wt|Wts) ----------------
template<int MODE, bool LAST>
__global__ __launch_bounds__(1024) void k_s(const bf16_t* __restrict__ xb,
                                            const bf16_t* __restrict__ Bmat,
                                            const float* __restrict__ bias,
                                            bf16_t* __restrict__ vTb,
                                            float* __restrict__ out) {
  const int blk = blockIdx.x;
  const int xcd = blk & 7, j = blk >> 3;
  const int bt = xcd * 2 + (j & 1);
  const int c = j >> 1;
  const int t = threadIdx.x;
  const int w = t >> 6, lane = t & 63;
  const int mrow = lane & 15, kg = lane >> 4;
  const int b0 = bt * 16;

  const bf16x8* ap = (const bf16x8*)(xb + (size_t)(b0 + mrow) * CK + w * 576) + kg;
  const bf16x8* bp = (const bf16x8*)(Bmat + ((size_t)c * CO + mrow) * CK + w * 576) + kg;
  f32x4 acc0 = {0.f, 0.f, 0.f, 0.f}, acc1 = {0.f, 0.f, 0.f, 0.f};
  #pragma unroll
  for (int s = 0; s < 18; s += 2) {
    acc0 = __builtin_amdgcn_mfma_f32_16x16x32_bf16(ap[s * 4], bp[s * 4], acc0, 0, 0, 0);
    acc1 = __builtin_amdgcn_mfma_f32_16x16x32_bf16(ap[(s + 1) * 4], bp[(s + 1) * 4], acc1, 0, 0, 0);
  }
  const f32x4 acc = acc0 + acc1;

  __shared__ float Ls[16][64][4];
  #pragma unroll
  for (int reg = 0; reg < 4; ++reg) Ls[w][lane][reg] = acc[reg];
  __syncthreads();
  if (t < 256) {
    const int row = t >> 4, col = t & 15;
    const int l = ((row >> 2) << 4) | col, reg = row & 3;
    float s = 0.f;
    #pragma unroll
    for (int q = 0; q < 16; ++q) s += Ls[q][l][reg];
    if (MODE == 0) s *= 0.1f;                // uniform c_ij = 1/10
    s += bias[c * CO + col];
    float n2 = s * s;
    #pragma unroll
    for (int m = 1; m < 16; m <<= 1) n2 += __shfl_xor(n2, m);
    const float vv = s * n2 / (1.f + n2) * rsqrtf(n2 + 1e-8f);
    if (LAST) out[(size_t)(b0 + row) * NCO + c * CO + col] = vv;
    else      vTb[(size_t)(c * CO + col) * CB + b0 + row] = (bf16_t)vv;
  }
}

// ---------------- agree + softmax + W-prescale: 144 blocks x 512 thr ----------------
// v-fragments read DIRECTLY from global vTb (L2-resident, already [co][b]);
// W-slice flat-staged to LDS (contiguous 40KB, 5 coalesced float4/thread).
template<bool FIRST>
__global__ __launch_bounds__(512) void k_asc(const float* __restrict__ x,
                                             const float* __restrict__ W,
                                             const bf16_t* __restrict__ vTb,
                                             const bf16_t* __restrict__ Wt,
                                             float* __restrict__ b_ij,
                                             bf16_t* __restrict__ Wts) {
  const int r0 = blockIdx.x * 8;
  const int t = threadIdx.x;
  const int h = t >> 8;            // class-half 0/1
  const int th = t & 255;
  const int w = th >> 6, lane = th & 63;
  const int mrow = lane & 15, kg = lane >> 4;

  __shared__ __align__(16) unsigned short xTl[64][CB + 8];   // 33.8 KB
  __shared__ float Wl[8][CC][CO][CI];                        // 40 KB [rl][c][o][i]
  __shared__ float agrL[8][CC];
  __shared__ float cwL[8][CC];

  // stage W-slice: contiguous 10240 floats = 2560 float4 (flat copy, coalesced)
  {
    const float4* wsrc = (const float4*)(W + (size_t)r0 * CC * CO * CI);
    float4* wdst = (float4*)&Wl[0][0][0][0];
    #pragma unroll
    for (int q = 0; q < 5; ++q) wdst[q * 512 + t] = wsrc[q * 512 + t];
  }
  // stage xTl[ri][b] = bf16(x[b][r0*8+ri])
  #pragma unroll
  for (int chunk = 0; chunk < 16; ++chunk) {
    const int b = chunk * 16 + (t >> 5);
    const int ri = (t & 31) * 2;
    const float2 v = *(const float2*)(x + (size_t)b * CK + r0 * 8 + ri);
    xTl[ri][b] = bfbits(v.x);
    xTl[ri + 1][b] = bfbits(v.y);
  }
  __syncthreads();

  bf16x8 a[8];
  #pragma unroll
  for (int s = 0; s < 8; ++s)
    a[s] = *(const bf16x8*)&xTl[w * 16 + mrow][s * 32 + kg * 8];

  const int o = lane & 15, g = lane >> 4;
  #pragma unroll
  for (int cc = 0; cc < 5; ++cc) {
    const int c = h * 5 + cc;
    f32x4 acc = {0.f, 0.f, 0.f, 0.f};
    #pragma unroll
    for (int s = 0; s < 8; ++s) {
      const bf16x8 bv = *(const bf16x8*)(vTb + (size_t)(c * CO + mrow) * CB + s * 32 + kg * 8);
      acc = __builtin_amdgcn_mfma_f32_16x16x32_bf16(a[s], bv, acc, 0, 0, 0);
    }
    float p = 0.f;
    #pragma unroll
    for (int reg = 0; reg < 4; ++reg) {
      const int m = g * 4 + reg, rl = m >> 3, i = m & 7;
      p += acc[reg] * Wl[w * 2 + rl][c][o][i];
    }
    #pragma unroll
    for (int msk = 1; msk < 32; msk <<= 1) p += __shfl_xor(p, msk);
    if ((lane & 31) == 0) agrL[w * 2 + (lane >> 5)][c] = p * (1.0f / CB);
  }
  __syncthreads();

  if (t < 8) {
    const int r = r0 + t;
    float nb[CC];
    float mx = -1e30f;
    #pragma unroll
    for (int c = 0; c < CC; ++c) {
      nb[c] = (FIRST ? 0.f : b_ij[r * CC + c]) + agrL[t][c];
      mx = fmaxf(mx, nb[c]);
    }
    float sum = 0.f;
    #pragma unroll
    for (int c = 0; c < CC; ++c) {
      b_ij[r * CC + c] = nb[c];
      const float e = __expf(nb[c] - mx);
      cwL[t][c] = e;
      sum += e;
    }
    const float inv = 1.f / sum;
    #pragma unroll
    for (int c = 0; c < CC; ++c) cwL[t][c] *= inv;
  }
  __syncthreads();

  #pragma unroll
  for (int q = 0; q < 3; ++q) {   // Wts = Wt * cw for this block's 8 r's (1280 slots)
    const int slot = q * 512 + t;
    if (slot < 1280) {
      const int co = slot >> 3, rl = slot & 7;
      const float cw = cwL[rl][co >> 4];
      const size_t off = (size_t)co * CK + (r0 + rl) * 8;
      const bf16x8 wv = *(const bf16x8*)(Wt + off);
      bf16x8 ov;
      #pragma unroll
      for (int jj = 0; jj < 8; ++jj) ov[jj] = (bf16_t)((float)wv[jj] * cw);
      *(bf16x8*)(Wts + off) = ov;
    }
  }
}

extern "C" void kernel_launch(void* const* d_in, const int* in_sizes, int n_in,
                              void* d_out, int out_size, void* d_ws, size_t ws_size,
                              hipStream_t stream) {
  const float* x    = (const float*)d_in[0];
  const float* W    = (const float*)d_in[1];
  const float* bias = (const float*)d_in[2];
  float* out = (float*)d_out;

  // ws: xb | Wt | Wts | vTb (bf16) | b_ij (f32)   (~10.7 MB)
  bf16_t* xb  = (bf16_t*)d_ws;
  bf16_t* Wt  = xb  + (size_t)CB * CK;
  bf16_t* Wts = Wt  + (size_t)NCO * CK;
  bf16_t* vTb = Wts + (size_t)NCO * CK;
  float*  b_ij = (float*)(vTb + (size_t)NCO * CB);

  // dedicated wide cvt (pure BW), then all-MFMA chain
  k_cvt<<<1872, 256, 0, stream>>>(x, W, xb, Wt);

  // iter 0 (uniform c_ij via 0.1 post-scale)
  k_s<0, false><<<160, 1024, 0, stream>>>(xb, Wt, bias, vTb, out);
  k_asc<true><<<144, 512, 0, stream>>>(x, W, vTb, Wt, b_ij, Wts);

  // iter 1
  k_s<1, false><<<160, 1024, 0, stream>>>(xb, Wts, bias, vTb, out);
  k_asc<false><<<144, 512, 0, stream>>>(x, W, vTb, Wt, b_ij, Wts);

  // iter 2 (final -> out)
  k_s<1, true><<<160, 1024, 0, stream>>>(xb, Wts, bias, vTb, out);
}

// Round 17
// 84.048 us; speedup vs baseline: 1.1635x; 1.1635x over previous
//
#include <hip/hip_runtime.h>

#define CB 256   // batch
#define CR 1152  // routes
#define CC 10    // class capsules
#define CO 16    // out dim
#define CI 8     // in dim
#define CK (CR*CI)   // 9216
#define NCO (CC*CO)  // 160

typedef __bf16 bf16_t;
typedef __attribute__((ext_vector_type(8))) __bf16 bf16x8;
typedef __attribute__((ext_vector_type(4))) float f32x4;

__device__ __forceinline__ unsigned short bfbits(float f) {
  union { __bf16 h; unsigned short u; } u; u.h = (bf16_t)f; return u.u;
}

// ---------------- cvt: pure-BW, fully coalesced reads ----------------
__global__ __launch_bounds__(256) void k_cvt(const float* __restrict__ x,
                                             const float* __restrict__ W,
                                             bf16_t* __restrict__ xb,
                                             bf16_t* __restrict__ Wt) {
  const int idx = blockIdx.x * 256 + threadIdx.x;
  const int NX = CB * CK / 8;              // 294912
  if (idx < NX) {
    const float4 f0 = ((const float4*)x)[idx * 2];
    const float4 f1 = ((const float4*)x)[idx * 2 + 1];
    bf16x8 o;
    o[0] = (bf16_t)f0.x; o[1] = (bf16_t)f0.y; o[2] = (bf16_t)f0.z; o[3] = (bf16_t)f0.w;
    o[4] = (bf16_t)f1.x; o[5] = (bf16_t)f1.y; o[6] = (bf16_t)f1.z; o[7] = (bf16_t)f1.w;
    ((bf16x8*)xb)[idx] = o;
  } else {
    const int wi = idx - NX;               // 0..184319, co fastest
    const int co = wi % NCO;               // c*16+o
    const int r  = wi / NCO;
    const float4* src = (const float4*)(W + ((size_t)r * NCO + co) * CI);
    const float4 f0 = src[0], f1 = src[1];
    bf16x8 v;
    v[0] = (bf16_t)f0.x; v[1] = (bf16_t)f0.y; v[2] = (bf16_t)f0.z; v[3] = (bf16_t)f0.w;
    v[4] = (bf16_t)f1.x; v[5] = (bf16_t)f1.y; v[6] = (bf16_t)f1.z; v[7] = (bf16_t)f1.w;
    *(bf16x8*)(Wt + (size_t)co * CK + r * 8) = v;
  }
}

// ---------------- s + squash: pure MFMA from xb / (Wt|Wts) ----------------
template<int MODE, bool LAST>
__global__ __launch_bounds__(1024) void k_s(const bf16_t* __restrict__ xb,
                                            const bf16_t* __restrict__ Bmat,
                                            const float* __restrict__ bias,
                                            bf16_t* __restrict__ vTb,
                                            float* __restrict__ out) {
  const int blk = blockIdx.x;
  const int xcd = blk & 7, j = blk >> 3;
  const int bt = xcd * 2 + (j & 1);
  const int c = j >> 1;
  const int t = threadIdx.x;
  const int w = t >> 6, lane = t & 63;
  const int mrow = lane & 15, kg = lane >> 4;
  const int b0 = bt * 16;

  const bf16x8* ap = (const bf16x8*)(xb + (size_t)(b0 + mrow) * CK + w * 576) + kg;
  const bf16x8* bp = (const bf16x8*)(Bmat + ((size_t)c * CO + mrow) * CK + w * 576) + kg;
  f32x4 acc0 = {0.f, 0.f, 0.f, 0.f}, acc1 = {0.f, 0.f, 0.f, 0.f};
  #pragma unroll
  for (int s = 0; s < 18; s += 2) {
    acc0 = __builtin_amdgcn_mfma_f32_16x16x32_bf16(ap[s * 4], bp[s * 4], acc0, 0, 0, 0);
    acc1 = __builtin_amdgcn_mfma_f32_16x16x32_bf16(ap[(s + 1) * 4], bp[(s + 1) * 4], acc1, 0, 0, 0);
  }
  const f32x4 acc = acc0 + acc1;

  __shared__ float Ls[16][64][4];
  #pragma unroll
  for (int reg = 0; reg < 4; ++reg) Ls[w][lane][reg] = acc[reg];
  __syncthreads();
  if (t < 256) {
    const int row = t >> 4, col = t & 15;
    const int l = ((row >> 2) << 4) | col, reg = row & 3;
    float s = 0.f;
    #pragma unroll
    for (int q = 0; q < 16; ++q) s += Ls[q][l][reg];
    if (MODE == 0) s *= 0.1f;                // uniform c_ij = 1/10
    s += bias[c * CO + col];
    float n2 = s * s;
    #pragma unroll
    for (int m = 1; m < 16; m <<= 1) n2 += __shfl_xor(n2, m);
    const float vv = s * n2 / (1.f + n2) * rsqrtf(n2 + 1e-8f);
    if (LAST) out[(size_t)(b0 + row) * NCO + c * CO + col] = vv;
    else      vTb[(size_t)(c * CO + col) * CB + b0 + row] = (bf16_t)vv;
  }
}

// ---------------- agree + softmax + W-prescale: 144 blocks x 512 thr ----------------
// Full staging: vL (coalesced, proven R14), xTl (transpose), Wl (flat 40KB copy).
// LDS total ~159.9 KB (1 block/CU, unchanged occupancy).
template<bool FIRST>
__global__ __launch_bounds__(512) void k_asc(const float* __restrict__ x,
                                             const float* __restrict__ W,
                                             const bf16_t* __restrict__ vTb,
                                             const bf16_t* __restrict__ Wt,
                                             float* __restrict__ b_ij,
                                             bf16_t* __restrict__ Wts) {
  const int r0 = blockIdx.x * 8;
  const int t = threadIdx.x;
  const int h = t >> 8;            // class-half 0/1
  const int th = t & 255;
  const int w = th >> 6, lane = th & 63;
  const int mrow = lane & 15, kg = lane >> 4;

  __shared__ __align__(16) unsigned short vL[NCO][CB + 8];   // 84.5 KB
  __shared__ __align__(16) unsigned short xTl[64][CB + 8];   // 33.8 KB
  __shared__ float Wl[8][CC][CO][CI];                        // 40 KB [rl][c][o][i]
  __shared__ float agrL[8][CC];
  __shared__ float cwL[8][CC];

  #pragma unroll
  for (int q = 0; q < 10; ++q) {   // stage vTb (5120 bf16x8, coalesced)
    const int idx = q * 512 + t;
    const int co = idx >> 5, bs = idx & 31;
    const bf16x8 v = ((const bf16x8*)vTb)[idx];
    *(bf16x8*)&vL[co][bs * 8] = v;
  }
  {                                 // stage W-slice: contiguous 2560 float4
    const float4* wsrc = (const float4*)(W + (size_t)r0 * CC * CO * CI);
    float4* wdst = (float4*)&Wl[0][0][0][0];
    #pragma unroll
    for (int q = 0; q < 5; ++q) wdst[q * 512 + t] = wsrc[q * 512 + t];
  }
  #pragma unroll
  for (int chunk = 0; chunk < 16; ++chunk) {  // stage xTl[ri][b] = bf16(x[b][r0*8+ri])
    const int b = chunk * 16 + (t >> 5);
    const int ri = (t & 31) * 2;
    const float2 v = *(const float2*)(x + (size_t)b * CK + r0 * 8 + ri);
    xTl[ri][b] = bfbits(v.x);
    xTl[ri + 1][b] = bfbits(v.y);
  }
  __syncthreads();

  bf16x8 a[8];
  #pragma unroll
  for (int s = 0; s < 8; ++s)
    a[s] = *(const bf16x8*)&xTl[w * 16 + mrow][s * 32 + kg * 8];

  const int o = lane & 15, g = lane >> 4;
  #pragma unroll
  for (int cc = 0; cc < 5; ++cc) {
    const int c = h * 5 + cc;
    f32x4 acc = {0.f, 0.f, 0.f, 0.f};
    #pragma unroll
    for (int s = 0; s < 8; ++s) {
      const bf16x8 bv = *(const bf16x8*)&vL[c * CO + mrow][s * 32 + kg * 8];
      acc = __builtin_amdgcn_mfma_f32_16x16x32_bf16(a[s], bv, acc, 0, 0, 0);
    }
    float p = 0.f;
    #pragma unroll
    for (int reg = 0; reg < 4; ++reg) {
      const int m = g * 4 + reg, rl = m >> 3, i = m & 7;
      p += acc[reg] * Wl[w * 2 + rl][c][o][i];
    }
    #pragma unroll
    for (int msk = 1; msk < 32; msk <<= 1) p += __shfl_xor(p, msk);
    if ((lane & 31) == 0) agrL[w * 2 + (lane >> 5)][c] = p * (1.0f / CB);
  }
  __syncthreads();

  if (t < 8) {
    const int r = r0 + t;
    float nb[CC];
    float mx = -1e30f;
    #pragma unroll
    for (int c = 0; c < CC; ++c) {
      nb[c] = (FIRST ? 0.f : b_ij[r * CC + c]) + agrL[t][c];
      mx = fmaxf(mx, nb[c]);
    }
    float sum = 0.f;
    #pragma unroll
    for (int c = 0; c < CC; ++c) {
      b_ij[r * CC + c] = nb[c];
      const float e = __expf(nb[c] - mx);
      cwL[t][c] = e;
      sum += e;
    }
    const float inv = 1.f / sum;
    #pragma unroll
    for (int c = 0; c < CC; ++c) cwL[t][c] *= inv;
  }
  __syncthreads();

  #pragma unroll
  for (int q = 0; q < 3; ++q) {   // Wts = Wt * cw for this block's 8 r's (1280 slots)
    const int slot = q * 512 + t;
    if (slot < 1280) {
      const int co = slot >> 3, rl = slot & 7;
      const float cw = cwL[rl][co >> 4];
      const size_t off = (size_t)co * CK + (r0 + rl) * 8;
      const bf16x8 wv = *(const bf16x8*)(Wt + off);
      bf16x8 ov;
      #pragma unroll
      for (int jj = 0; jj < 8; ++jj) ov[jj] = (bf16_t)((float)wv[jj] * cw);
      *(bf16x8*)(Wts + off) = ov;
    }
  }
}

extern "C" void kernel_launch(void* const* d_in, const int* in_sizes, int n_in,
                              void* d_out, int out_size, void* d_ws, size_t ws_size,
                              hipStream_t stream) {
  const float* x    = (const float*)d_in[0];
  const float* W    = (const float*)d_in[1];
  const float* bias = (const float*)d_in[2];
  float* out = (float*)d_out;

  // ws: xb | Wt | Wts | vTb (bf16) | b_ij (f32)   (~10.7 MB)
  bf16_t* xb  = (bf16_t*)d_ws;
  bf16_t* Wt  = xb  + (size_t)CB * CK;
  bf16_t* Wts = Wt  + (size_t)NCO * CK;
  bf16_t* vTb = Wts + (size_t)NCO * CK;
  float*  b_ij = (float*)(vTb + (size_t)NCO * CB);

  // dedicated wide cvt (pure BW), then all-MFMA chain
  k_cvt<<<1872, 256, 0, stream>>>(x, W, xb, Wt);

  // iter 0 (uniform c_ij via 0.1 post-scale)
  k_s<0, false><<<160, 1024, 0, stream>>>(xb, Wt, bias, vTb, out);
  k_asc<true><<<144, 512, 0, stream>>>(x, W, vTb, Wt, b_ij, Wts);

  // iter 1
  k_s<1, false><<<160, 1024, 0, stream>>>(xb, Wts, bias, vTb, out);
  k_asc<false><<<144, 512, 0, stream>>>(x, W, vTb, Wt, b_ij, Wts);

  // iter 2 (final -> out)
  k_s<1, true><<<160, 1024, 0, stream>>>(xb, Wts, bias, vTb, out);
}